// Round 5
// baseline (501.100 us; speedup 1.0000x reference)
//
#include <hip/hip_runtime.h>
#include <hip/hip_bf16.h>
#include <math.h>

#define NN 200000
#define NE 6400000

#define BSHIFT 9
#define BNODES 512                     // nodes per bucket
#define NB 391                         // ceil(NN / BNODES)
#define CAP 18432                      // bucket capacity (mean 16384, ~16 sigma headroom); mult of 4
#define S 4                            // stripes (LDS copies) per bucket
#define NBLK_SC 512
#define CHUNK (NE / NBLK_SC)           // 12500

// ---- workspace layout (4-byte words) ----
#define W_DACC 0                       // double (2 words, 8B-aligned at base)
#define W_UV   4                       // 8 floats
#define W_CUR  16                      // NB uints (bucket counts/cursors)
#define W_PART 512                     // NB*CAP u32 records: src | (dst_low<<18)
#define W_ACC  (W_PART + NB*CAP)       // S*6*NN f32 planar [(s*6+j)*NN+n]; reused for layer2
#define W_Z2   (W_ACC + S*6*NN)        // 2*NN f32 (float2/node); word offset even
#define W_TOTAL (W_Z2 + 2*NN)

// Native LDS float atomic add: fire-and-forget ds_add_f32 (no CAS loop, no
// fence, no return). Generic LDS address low 32 bits == DS byte offset.
__device__ __forceinline__ void ds_faddf(float* p, float v) {
    asm volatile("ds_add_f32 %0, %1" : : "v"((unsigned)(uintptr_t)p), "v"(v));
}

__global__ void k_init(unsigned* __restrict__ ws) {
    int t = blockIdx.x * blockDim.x + threadIdx.x;
    if (t == 0) *(double*)ws = 0.0;
    if (t < NB) ws[W_CUR + t] = 0u;
}

// u_i(h) = sum_o fc1[h][i][o]*attn1[h][o];  v_i(h) = sum_o fc1[h][i][o]*attn1[h][16+o]
__global__ void k_prep(const float* __restrict__ fc1, const float* __restrict__ attn1,
                       float* __restrict__ uv) {
    int t = threadIdx.x;
    if (t < 8) {
        int h = t >> 2, r = t & 3, i = r & 1, isv = r >> 1;
        double s = 0.0;
        for (int o = 0; o < 16; ++o)
            s += (double)fc1[h * 32 + i * 16 + o] * (double)attn1[h * 32 + isv * 16 + o];
        uv[t] = (float)s;
    }
}

// radix partition of edges by dst bucket; record = src(18b) | dst_low(9b)<<18
__global__ void k_scatter(const int* __restrict__ src, const int* __restrict__ dst,
                          unsigned* __restrict__ part, unsigned* __restrict__ cur) {
    __shared__ unsigned cnt[NB], gbase[NB], rk[NB];
    for (int i = threadIdx.x; i < NB; i += blockDim.x) { cnt[i] = 0u; rk[i] = 0u; }
    __syncthreads();
    int beg = blockIdx.x * CHUNK, end = beg + CHUNK;
    for (int i = beg + threadIdx.x; i < end; i += blockDim.x)
        atomicAdd(&cnt[dst[i] >> BSHIFT], 1u);        // native ds_add_u32 (int is native)
    __syncthreads();
    for (int i = threadIdx.x; i < NB; i += blockDim.x)
        gbase[i] = atomicAdd(&cur[i], cnt[i]);        // 391 global u32 atomics per block
    __syncthreads();
    for (int i = beg + threadIdx.x; i < end; i += blockDim.x) {
        int d = dst[i];
        int b = d >> BSHIFT;
        unsigned rank = atomicAdd(&rk[b], 1u);        // native ds_add_rtn_u32
        unsigned rec = (unsigned)__builtin_nontemporal_load(src + i) |
                       ((unsigned)(d & (BNODES - 1)) << 18);
        part[(size_t)b * CAP + gbase[b] + rank] = rec;
    }
}

// layer-1 edge pass: planar LDS accumulation {den0,A0,B0,den1,A1,B1}[node]
__launch_bounds__(256)
__global__ void k_gat1(const unsigned* __restrict__ part, const unsigned* __restrict__ cur,
                       const float2* __restrict__ h, const float* __restrict__ uv,
                       float* __restrict__ accc) {
    __shared__ float acc[6 * BNODES];                 // plane j at j*BNODES
    __shared__ float2 c01[BNODES];                    // per-dst {hd.v (head0), hd.v (head1)}
    int b = blockIdx.x >> 2, s = blockIdx.x & 3;
    int nodebase = b << BSHIFT;
    int nn = min(BNODES, NN - nodebase);
    float u00 = uv[0], u10 = uv[1], v00 = uv[2], v10 = uv[3];
    float u01 = uv[4], u11 = uv[5], v01 = uv[6], v11 = uv[7];
    for (int i = threadIdx.x; i < 6 * BNODES; i += 256) acc[i] = 0.f;
    for (int i = threadIdx.x; i < nn; i += 256) {
        float2 hd = h[nodebase + i];
        c01[i] = make_float2(fmaf(hd.x, v00, hd.y * v10), fmaf(hd.x, v01, hd.y * v11));
    }
    __syncthreads();
    int cnt = (int)cur[b];
    int Ls = (((cnt + S - 1) / S) + 3) & ~3;          // 4-aligned stripe length
    int lo = s * Ls, hi = min(cnt, lo + Ls);
    int len = hi - lo;
    if (len < 0) len = 0;
    int nvec = len & ~3;
    const unsigned* pb = part + (size_t)b * CAP;
    const uint4* pb4 = (const uint4*)(pb + lo);
    for (int q = threadIdx.x; q < (nvec >> 2); q += 256) {
        uint4 r4 = pb4[q];
#pragma unroll
        for (int k = 0; k < 4; ++k) {
            unsigned r = k == 0 ? r4.x : k == 1 ? r4.y : k == 2 ? r4.z : r4.w;
            int sn = r & 0x3FFFF;
            int dl = r >> 18;
            float2 hs = h[sn];
            float2 c = c01[dl];
            float e0 = fmaf(hs.x, u00, fmaf(hs.y, u10, c.x));
            float e1 = fmaf(hs.x, u01, fmaf(hs.y, u11, c.y));
            e0 = e0 >= 0.f ? e0 : 0.01f * e0;
            e1 = e1 >= 0.f ? e1 : 0.01f * e1;
            float ex0 = __expf(e0);
            float ex1 = __expf(e1);
            ds_faddf(&acc[0 * BNODES + dl], ex0);
            ds_faddf(&acc[1 * BNODES + dl], ex0 * hs.x);
            ds_faddf(&acc[2 * BNODES + dl], ex0 * hs.y);
            ds_faddf(&acc[3 * BNODES + dl], ex1);
            ds_faddf(&acc[4 * BNODES + dl], ex1 * hs.x);
            ds_faddf(&acc[5 * BNODES + dl], ex1 * hs.y);
        }
    }
    for (int i = lo + nvec + threadIdx.x; i < hi; i += 256) {
        unsigned r = pb[i];
        int sn = r & 0x3FFFF;
        int dl = r >> 18;
        float2 hs = h[sn];
        float2 c = c01[dl];
        float e0 = fmaf(hs.x, u00, fmaf(hs.y, u10, c.x));
        float e1 = fmaf(hs.x, u01, fmaf(hs.y, u11, c.y));
        e0 = e0 >= 0.f ? e0 : 0.01f * e0;
        e1 = e1 >= 0.f ? e1 : 0.01f * e1;
        float ex0 = __expf(e0);
        float ex1 = __expf(e1);
        ds_faddf(&acc[0 * BNODES + dl], ex0);
        ds_faddf(&acc[1 * BNODES + dl], ex0 * hs.x);
        ds_faddf(&acc[2 * BNODES + dl], ex0 * hs.y);
        ds_faddf(&acc[3 * BNODES + dl], ex1);
        ds_faddf(&acc[4 * BNODES + dl], ex1 * hs.x);
        ds_faddf(&acc[5 * BNODES + dl], ex1 * hs.y);
    }
    asm volatile("s_waitcnt lgkmcnt(0)" ::: "memory");
    __syncthreads();
#pragma unroll
    for (int j = 0; j < 6; ++j) {
        float* out = accc + ((size_t)(s * 6 + j)) * NN + nodebase;
        for (int w = threadIdx.x; w < nn; w += 256) out[w] = acc[j * BNODES + w];
    }
}

// reduce S stripe copies, finalize layer1 (softmax div + elu), z2 = x @ fc2
__global__ void k_node1(const float* __restrict__ accc, const float* __restrict__ fc1,
                        const float* __restrict__ fc2, float2* __restrict__ z2) {
    int n = blockIdx.x * blockDim.x + threadIdx.x;
    if (n >= NN) return;
    float a[6] = {0.f, 0.f, 0.f, 0.f, 0.f, 0.f};
#pragma unroll
    for (int sc = 0; sc < S; ++sc)
#pragma unroll
        for (int j = 0; j < 6; ++j)
            a[j] += accc[((size_t)(sc * 6 + j)) * NN + n];
    float den0 = a[0], A0 = a[1], B0 = a[2];
    float den1 = a[3], A1 = a[4], B1 = a[5];
    float x[32];
#pragma unroll
    for (int o = 0; o < 16; ++o) {
        float t0 = den0 > 0.f ? (A0 * fc1[o]      + B0 * fc1[16 + o]) / den0 : 0.f;
        float t1 = den1 > 0.f ? (A1 * fc1[32 + o] + B1 * fc1[48 + o]) / den1 : 0.f;
        x[o]      = t0 > 0.f ? t0 : expm1f(t0);
        x[16 + o] = t1 > 0.f ? t1 : expm1f(t1);
    }
    float z0 = 0.f, z1 = 0.f;
#pragma unroll
    for (int j = 0; j < 32; ++j) {
        z0 += x[j] * fc2[2 * j];
        z1 += x[j] * fc2[2 * j + 1];
    }
    z2[n] = make_float2(z0, z1);
}

// layer-2 edge pass: planar LDS accumulation {den,num0,num1}[node]; const exp shift 48
__launch_bounds__(256)
__global__ void k_gat2(const unsigned* __restrict__ part, const unsigned* __restrict__ cur,
                       const float2* __restrict__ z2, const float* __restrict__ attn2,
                       float* __restrict__ acc2c) {
    __shared__ float acc[3 * BNODES];
    __shared__ float cd[BNODES];
    int b = blockIdx.x >> 2, s = blockIdx.x & 3;
    int nodebase = b << BSHIFT;
    int nn = min(BNODES, NN - nodebase);
    float a0 = attn2[0], a1 = attn2[1], a2 = attn2[2], a3 = attn2[3];
    for (int i = threadIdx.x; i < 3 * BNODES; i += 256) acc[i] = 0.f;
    for (int i = threadIdx.x; i < nn; i += 256) {
        float2 zd = z2[nodebase + i];
        cd[i] = fmaf(zd.x, a2, zd.y * a3);
    }
    __syncthreads();
    int cnt = (int)cur[b];
    int Ls = (((cnt + S - 1) / S) + 3) & ~3;
    int lo = s * Ls, hi = min(cnt, lo + Ls);
    int len = hi - lo;
    if (len < 0) len = 0;
    int nvec = len & ~3;
    const unsigned* pb = part + (size_t)b * CAP;
    const uint4* pb4 = (const uint4*)(pb + lo);
    for (int q = threadIdx.x; q < (nvec >> 2); q += 256) {
        uint4 r4 = pb4[q];
#pragma unroll
        for (int k = 0; k < 4; ++k) {
            unsigned r = k == 0 ? r4.x : k == 1 ? r4.y : k == 2 ? r4.z : r4.w;
            int sn = r & 0x3FFFF;
            int dl = r >> 18;
            float2 zs = z2[sn];
            float e = fmaf(zs.x, a0, fmaf(zs.y, a1, cd[dl]));
            e = e >= 0.f ? e : 0.01f * e;
            float ex = __expf(e - 48.f);   // cancels in softmax; no overflow, den>=deg*e^-49
            ds_faddf(&acc[0 * BNODES + dl], ex);
            ds_faddf(&acc[1 * BNODES + dl], ex * zs.x);
            ds_faddf(&acc[2 * BNODES + dl], ex * zs.y);
        }
    }
    for (int i = lo + nvec + threadIdx.x; i < hi; i += 256) {
        unsigned r = pb[i];
        int sn = r & 0x3FFFF;
        int dl = r >> 18;
        float2 zs = z2[sn];
        float e = fmaf(zs.x, a0, fmaf(zs.y, a1, cd[dl]));
        e = e >= 0.f ? e : 0.01f * e;
        float ex = __expf(e - 48.f);
        ds_faddf(&acc[0 * BNODES + dl], ex);
        ds_faddf(&acc[1 * BNODES + dl], ex * zs.x);
        ds_faddf(&acc[2 * BNODES + dl], ex * zs.y);
    }
    asm volatile("s_waitcnt lgkmcnt(0)" ::: "memory");
    __syncthreads();
#pragma unroll
    for (int j = 0; j < 3; ++j) {
        float* out = acc2c + ((size_t)(s * 3 + j)) * NN + nodebase;
        for (int w = threadIdx.x; w < nn; w += 256) out[w] = acc[j * BNODES + w];
    }
}

// reduce stripes; x2 = num/den; f64 dot with mlp_w; block reduce; f64 atomic
__global__ void k_final(const float* __restrict__ acc2c, const float* __restrict__ mlp_w,
                        double* __restrict__ dacc) {
    int n = blockIdx.x * blockDim.x + threadIdx.x;
    double v = 0.0;
    if (n < NN) {
        float den = 0.f, n0 = 0.f, n1 = 0.f;
#pragma unroll
        for (int sc = 0; sc < S; ++sc) {
            den += acc2c[((size_t)(sc * 3 + 0)) * NN + n];
            n0  += acc2c[((size_t)(sc * 3 + 1)) * NN + n];
            n1  += acc2c[((size_t)(sc * 3 + 2)) * NN + n];
        }
        float x0 = den > 0.f ? n0 / den : 0.f;
        float x1 = den > 0.f ? n1 / den : 0.f;
        v = (double)x0 * (double)mlp_w[2 * n] + (double)x1 * (double)mlp_w[2 * n + 1];
    }
    for (int off = 32; off > 0; off >>= 1) v += __shfl_down(v, off);
    __shared__ double sm[4];
    int lane = threadIdx.x & 63, wid = threadIdx.x >> 6;
    if (lane == 0) sm[wid] = v;
    __syncthreads();
    if (threadIdx.x == 0) {
        double sum = sm[0] + sm[1] + sm[2] + sm[3];
        unsafeAtomicAdd(dacc, sum);   // ~800 device atomics total: negligible
    }
}

__global__ void k_out(const double* __restrict__ dacc, const float* __restrict__ mlp_b,
                      float* __restrict__ out) {
    double logit = dacc[0] + (double)mlp_b[0];
    out[0] = (float)(1.0 / (1.0 + exp(-logit)));
}

extern "C" void kernel_launch(void* const* d_in, const int* in_sizes, int n_in,
                              void* d_out, int out_size, void* d_ws, size_t ws_size,
                              hipStream_t stream) {
    const float* h     = (const float*)d_in[0];
    const int*   src   = (const int*)d_in[1];
    const int*   dst   = (const int*)d_in[2];
    const float* fc1   = (const float*)d_in[3];
    const float* attn1 = (const float*)d_in[4];
    const float* fc2   = (const float*)d_in[5];
    const float* attn2 = (const float*)d_in[6];
    const float* mlp_w = (const float*)d_in[7];
    const float* mlp_b = (const float*)d_in[8];
    float* out = (float*)d_out;

    unsigned* ws   = (unsigned*)d_ws;
    double*   dacc = (double*)d_ws;
    float*    uv   = (float*)(ws + W_UV);
    unsigned* cur  = ws + W_CUR;
    unsigned* part = ws + W_PART;
    float*    accc = (float*)(ws + W_ACC);   // layer1 stripe copies; reused for layer2
    float2*   z2   = (float2*)(ws + W_Z2);

    const int BLK = 256;
    const int NG  = (NN + BLK - 1) / BLK;

    hipLaunchKernelGGL(k_init, dim3(2), dim3(BLK), 0, stream, ws);
    hipLaunchKernelGGL(k_prep, dim3(1), dim3(64), 0, stream, fc1, attn1, uv);
    hipLaunchKernelGGL(k_scatter, dim3(NBLK_SC), dim3(BLK), 0, stream, src, dst, part, cur);
    hipLaunchKernelGGL(k_gat1, dim3(NB * S), dim3(BLK), 0, stream,
                       part, cur, (const float2*)h, uv, accc);
    hipLaunchKernelGGL(k_node1, dim3(NG), dim3(BLK), 0, stream, accc, fc1, fc2, z2);
    hipLaunchKernelGGL(k_gat2, dim3(NB * S), dim3(BLK), 0, stream,
                       part, cur, (const float2*)z2, attn2, accc);
    hipLaunchKernelGGL(k_final, dim3(NG), dim3(BLK), 0, stream, accc, mlp_w, dacc);
    hipLaunchKernelGGL(k_out, dim3(1), dim3(1), 0, stream, dacc, mlp_b, out);
}